// Round 4
// baseline (96.827 us; speedup 1.0000x reference)
//
#include <hip/hip_runtime.h>
#include <math.h>

#define WAVES_PER_BLOCK 4
#define RAYS_PER_WAVE 2   /* 2 independent rays interleaved per wave for ILP */

typedef float v2f __attribute__((ext_vector_type(2)));
typedef float v4f __attribute__((ext_vector_type(4)));

__device__ __forceinline__ v2f v2_fma(v2f a, v2f b, v2f c) {
    return __builtin_elementwise_fma(a, b, c);
}
__device__ __forceinline__ v2f v2_max0(v2f a) {
    return __builtin_elementwise_max(a, (v2f){0.0f, 0.0f});
}
__device__ __forceinline__ v2f v2_splat(float x) { return (v2f){x, x}; }

__device__ __forceinline__ float fast_rcp(float x) { return __builtin_amdgcn_rcpf(x); }

// ---------------- DPP cross-lane primitives (no LDS, ~2cyc) ----------------
#define DPP_ROW_SHR(n)  (0x110 | (n))
#define DPP_WF_SL1      0x130   /* lane i <- lane i+1 (shfl_down 1) */
#define DPP_WF_SR1      0x138   /* lane i <- lane i-1 (shfl_up 1)   */
#define DPP_ROW_BCAST15 0x142
#define DPP_ROW_BCAST31 0x143

template <int CTRL, int RM = 0xf, int BM = 0xf, bool BC = false>
__device__ __forceinline__ float fdpp(float old_, float src) {
    return __int_as_float(__builtin_amdgcn_update_dpp(
        __float_as_int(old_), __float_as_int(src), CTRL, RM, BM, BC));
}

__device__ __forceinline__ float lane63_bcast(float x) {
    return __int_as_float(__builtin_amdgcn_readlane(__float_as_int(x), 63));
}
// uniform broadcast of lane `l` (compile-time) through an SGPR — VALU only
__device__ __forceinline__ float rdlane(float x, int l) {
    return __int_as_float(__builtin_amdgcn_readlane(__float_as_int(x), l));
}

// inclusive scan-add across 64 lanes (canonical gfx9 DPP sequence)
__device__ __forceinline__ float scan_add_dpp(float x) {
    x += fdpp<DPP_ROW_SHR(1)>(0.0f, x);
    x += fdpp<DPP_ROW_SHR(2)>(0.0f, x);
    x += fdpp<DPP_ROW_SHR(4)>(0.0f, x);
    x += fdpp<DPP_ROW_SHR(8)>(0.0f, x);
    x += fdpp<DPP_ROW_BCAST15, 0xa>(0.0f, x);
    x += fdpp<DPP_ROW_BCAST31, 0xc>(0.0f, x);
    return x;
}
// inclusive scan-mul across 64 lanes (identity = 1.0)
__device__ __forceinline__ float scan_mul_dpp(float x) {
    x *= fdpp<DPP_ROW_SHR(1)>(1.0f, x);
    x *= fdpp<DPP_ROW_SHR(2)>(1.0f, x);
    x *= fdpp<DPP_ROW_SHR(4)>(1.0f, x);
    x *= fdpp<DPP_ROW_SHR(8)>(1.0f, x);
    x *= fdpp<DPP_ROW_BCAST15, 0xa>(1.0f, x);
    x *= fdpp<DPP_ROW_BCAST31, 0xc>(1.0f, x);
    return x;
}
__device__ __forceinline__ float wave_sum_dpp(float x) {
    return lane63_bcast(scan_add_dpp(x));
}

__device__ __forceinline__ float softplus_f(float x) {
    return fmaxf(x, 0.0f) + __logf(1.0f + __expf(-fabsf(x)));
}
__device__ __forceinline__ float sigmoid_f(float x) {
    return fast_rcp(1.0f + __expf(-x));
}
__device__ __forceinline__ float clamp1(float x) {
    return fminf(fmaxf(x, -1.0f), 1.0f);
}

// ---- 2-level rank over a sorted 64-entry wave-private LDS array ----------
// `own` = this lane's element (array[lane] == own): pivots a[8t+7] come from
// v_readlane; level 2 fetches the selected octant with two independent
// ds_read_b128.  Same count semantics as a binary search.
template <bool LE>
__device__ __forceinline__ int rank2(const float* a, float own, float x) {
    int o = 0;
#pragma unroll
    for (int t = 0; t < 8; ++t) {
        float p = rdlane(own, 8 * t + 7);
        o += (int)(LE ? (p <= x) : (p < x));
    }
    o = (o < 7) ? o : 7;            // x beyond a[63]: count within last octant
    const v4f q0 = *(const v4f*)&a[8 * o];
    const v4f q1 = *(const v4f*)&a[8 * o + 4];
    int cnt = 0;
    cnt += (int)(LE ? (q0.x <= x) : (q0.x < x));
    cnt += (int)(LE ? (q0.y <= x) : (q0.y < x));
    cnt += (int)(LE ? (q0.z <= x) : (q0.z < x));
    cnt += (int)(LE ? (q0.w <= x) : (q0.w < x));
    cnt += (int)(LE ? (q1.x <= x) : (q1.x < x));
    cnt += (int)(LE ? (q1.y <= x) : (q1.y < x));
    cnt += (int)(LE ? (q1.z <= x) : (q1.z < x));
    cnt += (int)(LE ? (q1.w <= x) : (q1.w < x));
    return 8 * o + cnt;
}

__global__ __launch_bounds__(WAVES_PER_BLOCK * 64)
void nerf_render_kernel(const float* __restrict__ rays_o,
                        const float* __restrict__ rays_d,
                        const float* __restrict__ W1,      // [3,64]
                        const float* __restrict__ b1,      // [64]
                        const float* __restrict__ w_sigma, // [64,1]
                        const float* __restrict__ b_sigma, // [1]
                        const float* __restrict__ W_rgb,   // [64,3]
                        const float* __restrict__ b_rgb,   // [3]
                        float* __restrict__ out)           // [N,3]
{
    const int tid  = threadIdx.x;
    const int lane = tid & 63;
    const int wv   = tid >> 6;
    // wave handles rays ray0, ray0+1 — two fully independent pipelines
    // interleaved in-register so each covers the other's stalls.
    const int ray0 = __builtin_amdgcn_readfirstlane(
        (blockIdx.x * WAVES_PER_BLOCK + wv) * RAYS_PER_WAVE);

    // Wave-private LDS (no __syncthreads anywhere); ray r at offset 64r/128r.
    __shared__ __align__(16) float s_cm  [WAVES_PER_BLOCK][RAYS_PER_WAVE * 128];
    __shared__ __align__(16) float s_zmid[WAVES_PER_BLOCK][RAYS_PER_WAVE * 64];
    __shared__ __align__(16) float s_cdf [WAVES_PER_BLOCK][RAYS_PER_WAVE * 64];
    __shared__ __align__(16) float s_zall[WAVES_PER_BLOCK][RAYS_PER_WAVE * 128];

    const float bs0 = b_sigma[0];
    const float br0 = b_rgb[0], br1 = b_rgb[1], br2 = b_rgb[2];

    float sample_dist[RAYS_PER_WAVE];
    float zc[RAYS_PER_WAVE];

    // ---- P0-P2: ray setup, near/far, per-ray affine layer-1 ----
#pragma unroll
    for (int r = 0; r < RAYS_PER_WAVE; ++r) {
        const int ray = ray0 + r;
        float ox = rays_o[ray * 3 + 0], oy = rays_o[ray * 3 + 1], oz = rays_o[ray * 3 + 2];
        float dx = rays_d[ray * 3 + 0], dy = rays_d[ray * 3 + 1], dz = rays_d[ray * 3 + 2];
        {
            float inv = __builtin_amdgcn_rsqf(dx * dx + dy * dy + dz * dz);
            dx *= inv; dy *= inv; dz *= inv;
        }
        float rx = fast_rcp(dx + 1e-15f);
        float ry = fast_rcp(dy + 1e-15f);
        float rz = fast_rcp(dz + 1e-15f);
        float t0x = (-1.0f - ox) * rx, t1x = (1.0f - ox) * rx;
        float t0y = (-1.0f - oy) * ry, t1y = (1.0f - oy) * ry;
        float t0z = (-1.0f - oz) * rz, t1z = (1.0f - oz) * rz;
        float nearv = fmaxf(fmaxf(fminf(t0x, t1x), fminf(t0y, t1y)), fminf(t0z, t1z));
        float farv  = fminf(fminf(fmaxf(t0x, t1x), fmaxf(t0y, t1y)), fmaxf(t0z, t1z));
        const bool miss = (farv < nearv);
        if (miss) { nearv = 1e9f; farv = 1e9f; }
        nearv = fmaxf(nearv, 0.05f);
        sample_dist[r] = (farv - nearv) * (1.0f / 64.0f);

        // layer-1 affine: a_j(z) = c_j + m_j*z; lane j owns unit j
        {
            float w1x = W1[lane], w1y = W1[64 + lane], w1z = W1[128 + lane];
            float eox = ox, eoy = oy, eoz = oz, msc = 1.0f;
            if (miss) {
                eox = clamp1(fmaf(dx, 1e9f, ox));
                eoy = clamp1(fmaf(dy, 1e9f, oy));
                eoz = clamp1(fmaf(dz, 1e9f, oz));
                msc = 0.0f;
            }
            float cj = fmaf(eox, w1x, fmaf(eoy, w1y, fmaf(eoz, w1z, b1[lane])));
            float mj = msc * fmaf(dx, w1x, fmaf(dy, w1y, dz * w1z));
            int g = (lane >> 1) * 4 + (lane & 1);
            s_cm[wv][128 * r + g]     = cj;
            s_cm[wv][128 * r + g + 2] = mj;
        }
        zc[r] = nearv + (farv - nearv) * ((float)lane * (1.0f / 63.0f));
    }

    // ---- P3: coarse MLP (sigma only), both rays share weight s_loads ----
    const v2f* ws2 = (const v2f*)w_sigma;
    v2f z2a = v2_splat(zc[0]), z2b = v2_splat(zc[1]);
    v2f accA = (v2f){bs0, 0.0f}, accB = (v2f){bs0, 0.0f};
#pragma unroll 4
    for (int t = 0; t < 32; ++t) {
        v2f wst = ws2[t];
        v4f ga = *(const v4f*)&s_cm[wv][4 * t];
        v4f gb = *(const v4f*)&s_cm[wv][128 + 4 * t];
        v2f ha = v2_max0(v2_fma((v2f){ga.z, ga.w}, z2a, (v2f){ga.x, ga.y}));
        v2f hb = v2_max0(v2_fma((v2f){gb.z, gb.w}, z2b, (v2f){gb.x, gb.y}));
        accA = v2_fma(ha, wst, accA);
        accB = v2_fma(hb, wst, accB);
    }
    float sigma[RAYS_PER_WAVE] = { softplus_f(accA.x + accA.y),
                                   softplus_f(accB.x + accB.y) };

    // ---- P4-P6: compositing, sample_pdf, rank-merge (per-ray, interleaved) --
    float nz[RAYS_PER_WAVE], zn[RAYS_PER_WAVE];
#pragma unroll
    for (int r = 0; r < RAYS_PER_WAVE; ++r) {
        zn[r] = fdpp<DPP_WF_SL1>(0.0f, zc[r]);
        float delta = (lane < 63) ? (zn[r] - zc[r]) : sample_dist[r];
        float alpha = 1.0f - __expf(-delta * sigma[r]);
        float v     = 1.0f - alpha + 1e-15f;
        float incl  = scan_mul_dpp(v);
        float trans = fdpp<DPP_WF_SR1>(1.0f, incl);
        float w = alpha * trans;

        float wgt = (lane >= 1 && lane <= 62) ? (w + 1e-5f) : 0.0f;
        float cumw = scan_add_dpp(wgt);
        float total = lane63_bcast(cumw);
        float cdf_incl = cumw * fast_rcp(total);

        float* zmR  = &s_zmid[wv][64 * r];
        float* cdfR = &s_cdf [wv][64 * r];
        float cdfv = (lane < 63) ? cdf_incl : 2.0f;
        zmR [lane] = (lane < 63) ? (0.5f * (zc[r] + zn[r])) : 0.0f;
        cdfR[lane] = cdfv;

        float u = 0.0078125f + (float)lane * 0.015625f;
        int ind = rank2<true>(cdfR, cdfv, u);
        int below = ind - 1;
        int above = (ind < 62) ? ind : 62;
        float cb = cdfR[below], ca = cdfR[above];
        float bb = zmR [below], ba = zmR [above];
        float denom = ca - cb;
        if (denom < 1e-5f) denom = 1.0f;
        float t = (u - cb) * fast_rcp(denom);
        nz[r] = fmaf(t, ba - bb, bb);
    }

    v2f za[RAYS_PER_WAVE];
#pragma unroll
    for (int r = 0; r < RAYS_PER_WAVE; ++r) {
        float* zmR  = &s_zmid[wv][64 * r];
        float* cdfR = &s_cdf [wv][64 * r];
        float* zaR  = &s_zall[wv][128 * r];
        zmR [lane] = zc[r];
        cdfR[lane] = nz[r];
        int pa = lane + rank2<false>(cdfR, nz[r], zc[r]);
        int pb = lane + rank2<true >(zmR,  zc[r], nz[r]);
        zaR[pa] = zc[r];
        zaR[pb] = nz[r];
    }
#pragma unroll
    for (int r = 0; r < RAYS_PER_WAVE; ++r)
        za[r] = *(const v2f*)&s_zall[wv][128 * r + 2 * lane];

    // ---- P7: fine MLP at both sample pairs of both rays; weights shared ----
    v2f zzA = za[0], zzB = za[1];
    v2f sA = v2_splat(bs0), rA = v2_splat(br0), gA = v2_splat(br1), bA = v2_splat(br2);
    v2f sB = v2_splat(bs0), rB = v2_splat(br0), gB = v2_splat(br1), bB = v2_splat(br2);
#pragma unroll 4
    for (int t = 0; t < 32; ++t) {
        int j0 = 2 * t, j1 = 2 * t + 1;
        float ws0 = w_sigma[j0], ws1 = w_sigma[j1];
        float wr0 = W_rgb[3 * j0 + 0], wg0 = W_rgb[3 * j0 + 1], wb0 = W_rgb[3 * j0 + 2];
        float wr1 = W_rgb[3 * j1 + 0], wg1 = W_rgb[3 * j1 + 1], wb1 = W_rgb[3 * j1 + 2];
        v4f ga = *(const v4f*)&s_cm[wv][4 * t];
        v4f gb = *(const v4f*)&s_cm[wv][128 + 4 * t];

        v2f hA0 = v2_max0(v2_fma(v2_splat(ga.z), zzA, v2_splat(ga.x)));
        v2f hB0 = v2_max0(v2_fma(v2_splat(gb.z), zzB, v2_splat(gb.x)));
        sA = v2_fma(hA0, v2_splat(ws0), sA);  sB = v2_fma(hB0, v2_splat(ws0), sB);
        rA = v2_fma(hA0, v2_splat(wr0), rA);  rB = v2_fma(hB0, v2_splat(wr0), rB);
        gA = v2_fma(hA0, v2_splat(wg0), gA);  gB = v2_fma(hB0, v2_splat(wg0), gB);
        bA = v2_fma(hA0, v2_splat(wb0), bA);  bB = v2_fma(hB0, v2_splat(wb0), bB);

        v2f hA1 = v2_max0(v2_fma(v2_splat(ga.w), zzA, v2_splat(ga.y)));
        v2f hB1 = v2_max0(v2_fma(v2_splat(gb.w), zzB, v2_splat(gb.y)));
        sA = v2_fma(hA1, v2_splat(ws1), sA);  sB = v2_fma(hB1, v2_splat(ws1), sB);
        rA = v2_fma(hA1, v2_splat(wr1), rA);  rB = v2_fma(hB1, v2_splat(wr1), rB);
        gA = v2_fma(hA1, v2_splat(wg1), gA);  gB = v2_fma(hB1, v2_splat(wg1), gB);
        bA = v2_fma(hA1, v2_splat(wb1), bA);  bB = v2_fma(hB1, v2_splat(wb1), bB);
    }

    // ---- P8: fine compositing + output, per ray ----
#pragma unroll
    for (int r = 0; r < RAYS_PER_WAVE; ++r) {
        v2f s2v = (r == 0) ? sA : sB;
        v2f r2v = (r == 0) ? rA : rB;
        v2f g2v = (r == 0) ? gA : gB;
        v2f b2v = (r == 0) ? bA : bB;
        float za0 = za[r].x, za1 = za[r].y;

        float sg0 = softplus_f(s2v.x), sg1 = softplus_f(s2v.y);
        float r0 = sigmoid_f(r2v.x),   r1 = sigmoid_f(r2v.y);
        float g0 = sigmoid_f(g2v.x),   g1 = sigmoid_f(g2v.y);
        float bl0 = sigmoid_f(b2v.x),  bl1 = sigmoid_f(b2v.y);

        float zn0 = fdpp<DPP_WF_SL1>(0.0f, za0);
        float d0 = za1 - za0;
        float d1 = (lane < 63) ? (zn0 - za1) : sample_dist[r];
        float a0 = 1.0f - __expf(-d0 * sg0);
        float a1 = 1.0f - __expf(-d1 * sg1);
        float v0 = 1.0f - a0 + 1e-15f;
        float v1 = 1.0f - a1 + 1e-15f;
        float local = v0 * v1;
        float incl2 = scan_mul_dpp(local);
        float eprod = fdpp<DPP_WF_SR1>(1.0f, incl2);
        float w0 = a0 * eprod;
        float w1 = a1 * (eprod * v0);

        float wsum = wave_sum_dpp(w0 + w1);
        float rs   = wave_sum_dpp(fmaf(w0, r0,  w1 * r1));
        float gs   = wave_sum_dpp(fmaf(w0, g0,  w1 * g1));
        float bs   = wave_sum_dpp(fmaf(w0, bl0, w1 * bl1));

        if (lane == r) {   // lane 0 writes ray0, lane 1 writes ray0+1
            float bg = 1.0f - wsum;
            const int ray = ray0 + r;
            out[ray * 3 + 0] = rs + bg;
            out[ray * 3 + 1] = gs + bg;
            out[ray * 3 + 2] = bs + bg;
        }
    }
}

extern "C" void kernel_launch(void* const* d_in, const int* in_sizes, int n_in,
                              void* d_out, int out_size, void* d_ws, size_t ws_size,
                              hipStream_t stream) {
    const float* rays_o  = (const float*)d_in[0];
    const float* rays_d  = (const float*)d_in[1];
    const float* W1      = (const float*)d_in[2];
    const float* b1      = (const float*)d_in[3];
    const float* w_sigma = (const float*)d_in[4];
    const float* b_sigma = (const float*)d_in[5];
    const float* W_rgb   = (const float*)d_in[6];
    const float* b_rgb   = (const float*)d_in[7];
    float* out = (float*)d_out;

    const int n_rays = in_sizes[0] / 3;
    const int rays_per_block = WAVES_PER_BLOCK * RAYS_PER_WAVE;
    dim3 grid((n_rays + rays_per_block - 1) / rays_per_block);
    dim3 block(WAVES_PER_BLOCK * 64);
    hipLaunchKernelGGL(nerf_render_kernel, grid, block, 0, stream,
                       rays_o, rays_d, W1, b1, w_sigma, b_sigma, W_rgb, b_rgb, out);
}

// Round 6
// 94.088 us; speedup vs baseline: 1.0291x; 1.0291x over previous
//
#include <hip/hip_runtime.h>
#include <math.h>

#define WAVES_PER_BLOCK 4

typedef float v2f __attribute__((ext_vector_type(2)));
typedef float v4f __attribute__((ext_vector_type(4)));

__device__ __forceinline__ float fast_rcp(float x) { return __builtin_amdgcn_rcpf(x); }

// ---------------- DPP cross-lane primitives (no LDS, ~2cyc) ----------------
#define DPP_ROW_SHR(n)  (0x110 | (n))
#define DPP_WF_SL1      0x130   /* lane i <- lane i+1 (shfl_down 1) */
#define DPP_WF_SR1      0x138   /* lane i <- lane i-1 (shfl_up 1)   */
#define DPP_ROW_BCAST15 0x142
#define DPP_ROW_BCAST31 0x143

template <int CTRL, int RM = 0xf, int BM = 0xf, bool BC = false>
__device__ __forceinline__ float fdpp(float old_, float src) {
    return __int_as_float(__builtin_amdgcn_update_dpp(
        __float_as_int(old_), __float_as_int(src), CTRL, RM, BM, BC));
}

__device__ __forceinline__ float lane63_bcast(float x) {
    return __int_as_float(__builtin_amdgcn_readlane(__float_as_int(x), 63));
}
// uniform broadcast of lane `l` (compile-time) through an SGPR — VALU only
__device__ __forceinline__ float rdlane(float x, int l) {
    return __int_as_float(__builtin_amdgcn_readlane(__float_as_int(x), l));
}

// inclusive scan-add across 64 lanes (canonical gfx9 DPP sequence)
__device__ __forceinline__ float scan_add_dpp(float x) {
    x += fdpp<DPP_ROW_SHR(1)>(0.0f, x);
    x += fdpp<DPP_ROW_SHR(2)>(0.0f, x);
    x += fdpp<DPP_ROW_SHR(4)>(0.0f, x);
    x += fdpp<DPP_ROW_SHR(8)>(0.0f, x);
    x += fdpp<DPP_ROW_BCAST15, 0xa>(0.0f, x);
    x += fdpp<DPP_ROW_BCAST31, 0xc>(0.0f, x);
    return x;
}
// inclusive scan-mul across 64 lanes (identity = 1.0)
__device__ __forceinline__ float scan_mul_dpp(float x) {
    x *= fdpp<DPP_ROW_SHR(1)>(1.0f, x);
    x *= fdpp<DPP_ROW_SHR(2)>(1.0f, x);
    x *= fdpp<DPP_ROW_SHR(4)>(1.0f, x);
    x *= fdpp<DPP_ROW_SHR(8)>(1.0f, x);
    x *= fdpp<DPP_ROW_BCAST15, 0xa>(1.0f, x);
    x *= fdpp<DPP_ROW_BCAST31, 0xc>(1.0f, x);
    return x;
}
__device__ __forceinline__ float wave_sum_dpp(float x) {
    return lane63_bcast(scan_add_dpp(x));
}

__device__ __forceinline__ float softplus_f(float x) {
    return fmaxf(x, 0.0f) + __logf(1.0f + __expf(-fabsf(x)));
}
__device__ __forceinline__ float sigmoid_f(float x) {
    return fast_rcp(1.0f + __expf(-x));
}
__device__ __forceinline__ float clamp1(float x) {
    return fminf(fmaxf(x, -1.0f), 1.0f);
}

// ---- 2-level rank over a SORTED 64-entry wave-private LDS array ----------
// `own` = this lane's element (array[lane] == own): pivots a[8t+7] come from
// v_readlane; level 2 fetches the selected octant with two independent
// ds_read_b128.  Same count semantics as a binary search.  SORTED input only!
template <bool LE>
__device__ __forceinline__ int rank2(const float* a, float own, float x) {
    int o = 0;
#pragma unroll
    for (int t = 0; t < 8; ++t) {
        float p = rdlane(own, 8 * t + 7);
        o += (int)(LE ? (p <= x) : (p < x));
    }
    o = (o < 7) ? o : 7;            // x beyond a[63]: count within last octant
    const v4f q0 = *(const v4f*)&a[8 * o];
    const v4f q1 = *(const v4f*)&a[8 * o + 4];
    int cnt = 0;
    cnt += (int)(LE ? (q0.x <= x) : (q0.x < x));
    cnt += (int)(LE ? (q0.y <= x) : (q0.y < x));
    cnt += (int)(LE ? (q0.z <= x) : (q0.z < x));
    cnt += (int)(LE ? (q0.w <= x) : (q0.w < x));
    cnt += (int)(LE ? (q1.x <= x) : (q1.x < x));
    cnt += (int)(LE ? (q1.y <= x) : (q1.y < x));
    cnt += (int)(LE ? (q1.z <= x) : (q1.z < x));
    cnt += (int)(LE ? (q1.w <= x) : (q1.w < x));
    return 8 * o + cnt;
}

__global__ __launch_bounds__(WAVES_PER_BLOCK * 64)
void nerf_render_kernel(const float* __restrict__ rays_o,
                        const float* __restrict__ rays_d,
                        const float* __restrict__ W1,      // [3,64]
                        const float* __restrict__ b1,      // [64]
                        const float* __restrict__ w_sigma, // [64,1]
                        const float* __restrict__ b_sigma, // [1]
                        const float* __restrict__ W_rgb,   // [64,3]
                        const float* __restrict__ b_rgb,   // [3]
                        float* __restrict__ out)           // [N,3]
{
    const int tid  = threadIdx.x;
    const int lane = tid & 63;
    const int wv   = tid >> 6;
    const int ray  = __builtin_amdgcn_readfirstlane(blockIdx.x * WAVES_PER_BLOCK + wv);

    // Wave-private LDS; intra-wave DS ops are program-ordered -> no barriers.
    // s_pref doubles as the knee-delta scatter buffer and then the prefix
    // table [65 slots][8: {G_s,GK_s,G_r,GK_r,G_g,GK_g,G_b,GK_b}].
    __shared__ __align__(16) float s_pref[WAVES_PER_BLOCK][65][8];
    __shared__ __align__(16) float s_kne [WAVES_PER_BLOCK][64];  // sorted knees
    __shared__ __align__(16) float s_zmid[WAVES_PER_BLOCK][64];  // unsorted knees, then zmid/z
    __shared__ __align__(16) float s_cdf [WAVES_PER_BLOCK][64];
    __shared__ __align__(16) float s_zall[WAVES_PER_BLOCK][128];

    // ---- ray load + normalize ----
    float ox = rays_o[ray * 3 + 0], oy = rays_o[ray * 3 + 1], oz = rays_o[ray * 3 + 2];
    float dx = rays_d[ray * 3 + 0], dy = rays_d[ray * 3 + 1], dz = rays_d[ray * 3 + 2];
    {
        float inv = __builtin_amdgcn_rsqf(dx * dx + dy * dy + dz * dz);
        dx *= inv; dy *= inv; dz *= inv;
    }

    // ---- near/far vs [-1,1]^3 ----
    float rx = fast_rcp(dx + 1e-15f);
    float ry = fast_rcp(dy + 1e-15f);
    float rz = fast_rcp(dz + 1e-15f);
    float t0x = (-1.0f - ox) * rx, t1x = (1.0f - ox) * rx;
    float t0y = (-1.0f - oy) * ry, t1y = (1.0f - oy) * ry;
    float t0z = (-1.0f - oz) * rz, t1z = (1.0f - oz) * rz;
    float nearv = fmaxf(fmaxf(fminf(t0x, t1x), fminf(t0y, t1y)), fminf(t0z, t1z));
    float farv  = fminf(fminf(fmaxf(t0x, t1x), fmaxf(t0y, t1y)), fmaxf(t0z, t1z));
    const bool miss = (farv < nearv);
    if (miss) { nearv = 1e9f; farv = 1e9f; }
    nearv = fmaxf(nearv, 0.05f);
    const float sample_dist = (farv - nearv) * (1.0f / 64.0f);

    // ---- per-lane unit weights (lane j owns hidden unit j) ----
    const float wS = w_sigma[lane];
    const float wR = W_rgb[3 * lane + 0];
    const float wG = W_rgb[3 * lane + 1];
    const float wB = W_rgb[3 * lane + 2];

    // ---- per-ray affine layer-1: a_j(z) = c_j + m_j*z ----
    float cj, mj;
    {
        float w1x = W1[lane], w1y = W1[64 + lane], w1z = W1[128 + lane];
        float eox = ox, eoy = oy, eoz = oz, msc = 1.0f;
        if (miss) {
            eox = clamp1(fmaf(dx, 1e9f, ox));
            eoy = clamp1(fmaf(dy, 1e9f, oy));
            eoz = clamp1(fmaf(dz, 1e9f, oz));
            msc = 0.0f;
        }
        cj = fmaf(eox, w1x, fmaf(eoy, w1y, fmaf(eoz, w1z, b1[lane])));
        mj = msc * fmaf(dx, w1x, fmaf(dy, w1y, dz * w1z));
    }

    // ---- piecewise-linear MLP setup --------------------------------------
    // relu(c+mz) = (c+mz)/2 + (|m|/2)|z-knee|, knee = -c/m (exact identity).
    // pre_X(z) = PpX + QpX*z + 2*(PrefG_k*z - PrefGK_k), k = #knees < z.
    const bool m0 = (mj == 0.0f);           // includes all lanes of miss rays
    float knee = m0 ? 3e38f : (-cj * fast_rcp(mj));
    float sgn  = (mj > 0.0f) ? 1.0f : -1.0f;
    float hm   = 0.5f * fabsf(mj);                    // |m|/2   (m0 -> 0)
    float hk   = m0 ? 0.0f : (-0.5f * cj * sgn);      // g*knee computed stably
    float pb   = m0 ? fmaxf(cj, 0.0f) : (0.5f * cj);  // P contribution / wX
    float qb   = 0.5f * mj;                           // Q contribution / wX

    float gS = wS * hm, gR = wR * hm, gG = wG * hm, gB = wB * hm;
    float kS = wS * hk, kR = wR * hk, kG = wG * hk, kB = wB * hk;

    float* kneeU = s_zmid[wv];   // unsorted knees (dead after the rank below)
    float* kneeS = s_kne[wv];
    kneeU[lane] = knee;
    {
        v4f z4 = (v4f){0.0f, 0.0f, 0.0f, 0.0f};
        *(v4f*)&s_pref[wv][lane][0] = z4;   // zero delta slots first
        *(v4f*)&s_pref[wv][lane][4] = z4;
    }
    // ---- sorted position of own knee over the UNSORTED array -------------
    // (rank2 requires sorted input — the round-5 bug was using it here.)
    // Brute-force count with stable tie-break (j < lane) => bijective scatter
    // even for equal knees (e.g. the all-3e38 miss-ray group).
    int p = 0;
#pragma unroll
    for (int g = 0; g < 16; ++g) {
        v4f q = *(const v4f*)&kneeU[4 * g];
        int j = 4 * g;
        p += (int)((q.x < knee) || ((q.x == knee) && (j + 0 < lane)));
        p += (int)((q.y < knee) || ((q.y == knee) && (j + 1 < lane)));
        p += (int)((q.z < knee) || ((q.z == knee) && (j + 2 < lane)));
        p += (int)((q.w < knee) || ((q.w == knee) && (j + 3 < lane)));
    }
    kneeS[p] = knee;
    *(v4f*)&s_pref[wv][p][0] = (v4f){gS, kS, gR, kR};
    *(v4f*)&s_pref[wv][p][4] = (v4f){gG, kG, gB, kB};

    // read back in sorted order, scan, build prefix table (slot k = sum p<k)
    v4f d0 = *(const v4f*)&s_pref[wv][lane][0];
    v4f d1 = *(const v4f*)&s_pref[wv][lane][4];
    float own_knee = kneeS[lane];

    float iGs = scan_add_dpp(d0.x), iKs = scan_add_dpp(d0.y);
    float iGr = scan_add_dpp(d0.z), iKr = scan_add_dpp(d0.w);
    float iGg = scan_add_dpp(d1.x), iKg = scan_add_dpp(d1.y);
    float iGb = scan_add_dpp(d1.z), iKb = scan_add_dpp(d1.w);
    float GtS = lane63_bcast(iGs), KtS = lane63_bcast(iKs);
    float GtR = lane63_bcast(iGr), KtR = lane63_bcast(iKr);
    float GtG = lane63_bcast(iGg), KtG = lane63_bcast(iKg);
    float GtB = lane63_bcast(iGb), KtB = lane63_bcast(iKb);

    *(v4f*)&s_pref[wv][lane + 1][0] = (v4f){iGs, iKs, iGr, iKr};
    *(v4f*)&s_pref[wv][lane + 1][4] = (v4f){iGg, iKg, iGb, iKb};
    if (lane == 0) {
        v4f z4 = (v4f){0.0f, 0.0f, 0.0f, 0.0f};
        *(v4f*)&s_pref[wv][0][0] = z4;
        *(v4f*)&s_pref[wv][0][4] = z4;
    }

    // affine totals (order-independent sums) + fold suffix totals and biases
    float PS = wave_sum_dpp(wS * pb), QS = wave_sum_dpp(wS * qb);
    float PR = wave_sum_dpp(wR * pb), QR = wave_sum_dpp(wR * qb);
    float PG = wave_sum_dpp(wG * pb), QG = wave_sum_dpp(wG * qb);
    float PB = wave_sum_dpp(wB * pb), QB = wave_sum_dpp(wB * qb);
    const float bs0 = b_sigma[0];
    const float PpS = PS + KtS + bs0,      QpS = QS - GtS;
    const float PpR = PR + KtR + b_rgb[0], QpR = QR - GtR;
    const float PpG = PG + KtG + b_rgb[1], QpG = QG - GtG;
    const float PpB = PB + KtB + b_rgb[2], QpB = QB - GtB;

    // ---- coarse samples + sigma via piecewise eval ----
    float z = nearv + (farv - nearv) * ((float)lane * (1.0f / 63.0f));
    float sigma;
    {
        int k = rank2<false>(kneeS, own_knee, z);
        v2f pk = *(const v2f*)&s_pref[wv][k][0];   // {G_s, GK_s}
        float pre = fmaf(2.0f, fmaf(pk.x, z, -pk.y), fmaf(QpS, z, PpS));
        sigma = softplus_f(pre);
    }

    // ---- coarse alpha compositing -> weights ----
    float z_next = fdpp<DPP_WF_SL1>(0.0f, z);
    float delta  = (lane < 63) ? (z_next - z) : sample_dist;
    float alpha  = 1.0f - __expf(-delta * sigma);
    float v      = 1.0f - alpha + 1e-15f;
    float incl   = scan_mul_dpp(v);
    float trans  = fdpp<DPP_WF_SR1>(1.0f, incl);   // lane0 -> 1.0
    float w = alpha * trans;

    // ---- sample_pdf: unnormalized scan, total from lane63 of same scan ----
    float wgt = (lane >= 1 && lane <= 62) ? (w + 1e-5f) : 0.0f;
    float cumw = scan_add_dpp(wgt);
    float total = lane63_bcast(cumw);
    float cdf_incl = cumw * fast_rcp(total);

    float zmid = 0.5f * (z + z_next);
    float cdfv = (lane < 63) ? cdf_incl : 2.0f;    // sentinel
    s_zmid[wv][lane] = (lane < 63) ? zmid : 0.0f;  // kneeU dead -> reuse
    s_cdf [wv][lane] = cdfv;

    float u = 0.0078125f + (float)lane * 0.015625f;
    int ind = rank2<true>(s_cdf[wv], cdfv, u);
    int below = ind - 1;
    int above = (ind < 62) ? ind : 62;
    float cb = s_cdf[wv][below], ca = s_cdf[wv][above];
    float bb = s_zmid[wv][below], ba = s_zmid[wv][above];
    float denom = ca - cb;
    if (denom < 1e-5f) denom = 1.0f;
    float t = (u - cb) * fast_rcp(denom);
    float nz = fmaf(t, ba - bb, bb);

    // ---- rank-merge concat(z, new_z) -> 128 sorted ----
    s_zmid[wv][lane] = z;      // array of z's   (z_lane == own)
    s_cdf [wv][lane] = nz;     // array of nz's  (nz     == own)
    int pa  = lane + rank2<false>(s_cdf [wv], nz, z);
    int pb2 = lane + rank2<true >(s_zmid[wv], z,  nz);
    s_zall[wv][pa]  = z;
    s_zall[wv][pb2] = nz;

    v2f za = *(const v2f*)&s_zall[wv][2 * lane];
    float za0 = za.x;
    float za1 = za.y;

    // ---- fine MLP via piecewise eval (both samples, all 4 channels) ----
    int k0 = rank2<false>(kneeS, own_knee, za0);
    int k1 = rank2<false>(kneeS, own_knee, za1);
    v4f A0 = *(const v4f*)&s_pref[wv][k0][0];
    v4f A1 = *(const v4f*)&s_pref[wv][k0][4];
    v4f B0 = *(const v4f*)&s_pref[wv][k1][0];
    v4f B1 = *(const v4f*)&s_pref[wv][k1][4];

    float pS0 = fmaf(2.0f, fmaf(A0.x, za0, -A0.y), fmaf(QpS, za0, PpS));
    float pR0 = fmaf(2.0f, fmaf(A0.z, za0, -A0.w), fmaf(QpR, za0, PpR));
    float pG0 = fmaf(2.0f, fmaf(A1.x, za0, -A1.y), fmaf(QpG, za0, PpG));
    float pB0 = fmaf(2.0f, fmaf(A1.z, za0, -A1.w), fmaf(QpB, za0, PpB));
    float pS1 = fmaf(2.0f, fmaf(B0.x, za1, -B0.y), fmaf(QpS, za1, PpS));
    float pR1 = fmaf(2.0f, fmaf(B0.z, za1, -B0.w), fmaf(QpR, za1, PpR));
    float pG1 = fmaf(2.0f, fmaf(B1.x, za1, -B1.y), fmaf(QpG, za1, PpG));
    float pB1 = fmaf(2.0f, fmaf(B1.z, za1, -B1.w), fmaf(QpB, za1, PpB));

    float sg0 = softplus_f(pS0), sg1 = softplus_f(pS1);
    float r0 = sigmoid_f(pR0),   r1 = sigmoid_f(pR1);
    float g0 = sigmoid_f(pG0),   g1 = sigmoid_f(pG1);
    float bl0 = sigmoid_f(pB0),  bl1 = sigmoid_f(pB1);

    // ---- fine compositing over 128 samples (2/lane) ----
    float zn0 = fdpp<DPP_WF_SL1>(0.0f, za0);
    float d0f = za1 - za0;
    float d1f = (lane < 63) ? (zn0 - za1) : sample_dist;
    float a0 = 1.0f - __expf(-d0f * sg0);
    float a1 = 1.0f - __expf(-d1f * sg1);
    float v0 = 1.0f - a0 + 1e-15f;
    float v1 = 1.0f - a1 + 1e-15f;
    float local = v0 * v1;
    float incl2 = scan_mul_dpp(local);
    float eprod = fdpp<DPP_WF_SR1>(1.0f, incl2);   // lane0 -> 1.0
    float w0 = a0 * eprod;
    float w1 = a1 * (eprod * v0);

    float wsum = wave_sum_dpp(w0 + w1);
    float rs   = wave_sum_dpp(fmaf(w0, r0,  w1 * r1));
    float gs   = wave_sum_dpp(fmaf(w0, g0,  w1 * g1));
    float bs   = wave_sum_dpp(fmaf(w0, bl0, w1 * bl1));

    if (lane == 0) {
        float bg = 1.0f - wsum;
        out[ray * 3 + 0] = rs + bg;
        out[ray * 3 + 1] = gs + bg;
        out[ray * 3 + 2] = bs + bg;
    }
}

extern "C" void kernel_launch(void* const* d_in, const int* in_sizes, int n_in,
                              void* d_out, int out_size, void* d_ws, size_t ws_size,
                              hipStream_t stream) {
    const float* rays_o  = (const float*)d_in[0];
    const float* rays_d  = (const float*)d_in[1];
    const float* W1      = (const float*)d_in[2];
    const float* b1      = (const float*)d_in[3];
    const float* w_sigma = (const float*)d_in[4];
    const float* b_sigma = (const float*)d_in[5];
    const float* W_rgb   = (const float*)d_in[6];
    const float* b_rgb   = (const float*)d_in[7];
    float* out = (float*)d_out;

    const int n_rays = in_sizes[0] / 3;
    dim3 grid((n_rays + WAVES_PER_BLOCK - 1) / WAVES_PER_BLOCK);
    dim3 block(WAVES_PER_BLOCK * 64);
    hipLaunchKernelGGL(nerf_render_kernel, grid, block, 0, stream,
                       rays_o, rays_d, W1, b1, w_sigma, b_sigma, W_rgb, b_rgb, out);
}

// Round 7
// 90.609 us; speedup vs baseline: 1.0686x; 1.0384x over previous
//
#include <hip/hip_runtime.h>
#include <math.h>

#define WAVES_PER_BLOCK 4

typedef float v2f __attribute__((ext_vector_type(2)));
typedef float v4f __attribute__((ext_vector_type(4)));

__device__ __forceinline__ float fast_rcp(float x) { return __builtin_amdgcn_rcpf(x); }

// ---------------- DPP cross-lane primitives (no LDS, ~2cyc) ----------------
#define DPP_ROW_SHR(n)  (0x110 | (n))
#define DPP_WF_SL1      0x130   /* lane i <- lane i+1 (shfl_down 1) */
#define DPP_WF_SR1      0x138   /* lane i <- lane i-1 (shfl_up 1)   */
#define DPP_ROW_BCAST15 0x142
#define DPP_ROW_BCAST31 0x143

template <int CTRL, int RM = 0xf, int BM = 0xf, bool BC = false>
__device__ __forceinline__ float fdpp(float old_, float src) {
    return __int_as_float(__builtin_amdgcn_update_dpp(
        __float_as_int(old_), __float_as_int(src), CTRL, RM, BM, BC));
}

__device__ __forceinline__ float lane63_bcast(float x) {
    return __int_as_float(__builtin_amdgcn_readlane(__float_as_int(x), 63));
}
// uniform broadcast of lane `l` (compile-time) through an SGPR — VALU only
__device__ __forceinline__ float rdlane(float x, int l) {
    return __int_as_float(__builtin_amdgcn_readlane(__float_as_int(x), l));
}

// inclusive scan-add across 64 lanes (each step = ONE v_add_f32_dpp)
__device__ __forceinline__ float scan_add_dpp(float x) {
    x += fdpp<DPP_ROW_SHR(1)>(0.0f, x);
    x += fdpp<DPP_ROW_SHR(2)>(0.0f, x);
    x += fdpp<DPP_ROW_SHR(4)>(0.0f, x);
    x += fdpp<DPP_ROW_SHR(8)>(0.0f, x);
    x += fdpp<DPP_ROW_BCAST15, 0xa>(0.0f, x);
    x += fdpp<DPP_ROW_BCAST31, 0xc>(0.0f, x);
    return x;
}
// inclusive scan-mul across 64 lanes (identity = 1.0)
__device__ __forceinline__ float scan_mul_dpp(float x) {
    x *= fdpp<DPP_ROW_SHR(1)>(1.0f, x);
    x *= fdpp<DPP_ROW_SHR(2)>(1.0f, x);
    x *= fdpp<DPP_ROW_SHR(4)>(1.0f, x);
    x *= fdpp<DPP_ROW_SHR(8)>(1.0f, x);
    x *= fdpp<DPP_ROW_BCAST15, 0xa>(1.0f, x);
    x *= fdpp<DPP_ROW_BCAST31, 0xc>(1.0f, x);
    return x;
}
__device__ __forceinline__ float wave_sum_dpp(float x) {
    return lane63_bcast(scan_add_dpp(x));
}

__device__ __forceinline__ float softplus_f(float x) {
    return fmaxf(x, 0.0f) + __logf(1.0f + __expf(-fabsf(x)));
}
__device__ __forceinline__ float sigmoid_f(float x) {
    return fast_rcp(1.0f + __expf(-x));
}
__device__ __forceinline__ float clamp1(float x) {
    return fminf(fmaxf(x, -1.0f), 1.0f);
}

// ---- 2-level rank over a SORTED 64-entry wave-private LDS array ----------
// `own` = this lane's element (array[lane] == own): pivots a[8t+7] come from
// v_readlane; level 2 fetches the selected octant with two independent
// ds_read_b128.  Same count semantics as a binary search.  SORTED input only!
template <bool LE>
__device__ __forceinline__ int rank2(const float* a, float own, float x) {
    int o = 0;
#pragma unroll
    for (int t = 0; t < 8; ++t) {
        float p = rdlane(own, 8 * t + 7);
        o += (int)(LE ? (p <= x) : (p < x));
    }
    o = (o < 7) ? o : 7;            // x beyond a[63]: count within last octant
    const v4f q0 = *(const v4f*)&a[8 * o];
    const v4f q1 = *(const v4f*)&a[8 * o + 4];
    int cnt = 0;
    cnt += (int)(LE ? (q0.x <= x) : (q0.x < x));
    cnt += (int)(LE ? (q0.y <= x) : (q0.y < x));
    cnt += (int)(LE ? (q0.z <= x) : (q0.z < x));
    cnt += (int)(LE ? (q0.w <= x) : (q0.w < x));
    cnt += (int)(LE ? (q1.x <= x) : (q1.x < x));
    cnt += (int)(LE ? (q1.y <= x) : (q1.y < x));
    cnt += (int)(LE ? (q1.z <= x) : (q1.z < x));
    cnt += (int)(LE ? (q1.w <= x) : (q1.w < x));
    return 8 * o + cnt;
}

__global__ __launch_bounds__(WAVES_PER_BLOCK * 64)
void nerf_render_kernel(const float* __restrict__ rays_o,
                        const float* __restrict__ rays_d,
                        const float* __restrict__ W1,      // [3,64]
                        const float* __restrict__ b1,      // [64]
                        const float* __restrict__ w_sigma, // [64,1]
                        const float* __restrict__ b_sigma, // [1]
                        const float* __restrict__ W_rgb,   // [64,3]
                        const float* __restrict__ b_rgb,   // [3]
                        float* __restrict__ out)           // [N,3]
{
    const int tid  = threadIdx.x;
    const int lane = tid & 63;
    const int wv   = tid >> 6;
    const int ray  = __builtin_amdgcn_readfirstlane(blockIdx.x * WAVES_PER_BLOCK + wv);

    // Wave-private LDS; intra-wave DS ops are program-ordered -> no barriers.
    // s_pref: table [65 slots][8: {A_s,B_s,A_r,B_r,A_g,B_g,A_b,B_b}] where
    // pre_X(z) = fma(A_k, z, B_k), k = #knees < z  (A=Qp+prefA, B=Pp+prefB).
    __shared__ __align__(16) float s_pref[WAVES_PER_BLOCK][65][8];
    __shared__ __align__(16) float s_kne [WAVES_PER_BLOCK][64];  // sorted knees
    __shared__ __align__(16) float s_zmid[WAVES_PER_BLOCK][64];  // keys, then zmid/z
    __shared__ __align__(16) float s_cdf [WAVES_PER_BLOCK][64];
    __shared__ __align__(16) float s_zall[WAVES_PER_BLOCK][128];

    // ---- ray load + normalize ----
    float ox = rays_o[ray * 3 + 0], oy = rays_o[ray * 3 + 1], oz = rays_o[ray * 3 + 2];
    float dx = rays_d[ray * 3 + 0], dy = rays_d[ray * 3 + 1], dz = rays_d[ray * 3 + 2];
    {
        float inv = __builtin_amdgcn_rsqf(dx * dx + dy * dy + dz * dz);
        dx *= inv; dy *= inv; dz *= inv;
    }

    // ---- near/far vs [-1,1]^3 ----
    float rx = fast_rcp(dx + 1e-15f);
    float ry = fast_rcp(dy + 1e-15f);
    float rz = fast_rcp(dz + 1e-15f);
    float t0x = (-1.0f - ox) * rx, t1x = (1.0f - ox) * rx;
    float t0y = (-1.0f - oy) * ry, t1y = (1.0f - oy) * ry;
    float t0z = (-1.0f - oz) * rz, t1z = (1.0f - oz) * rz;
    float nearv = fmaxf(fmaxf(fminf(t0x, t1x), fminf(t0y, t1y)), fminf(t0z, t1z));
    float farv  = fminf(fminf(fmaxf(t0x, t1x), fmaxf(t0y, t1y)), fmaxf(t0z, t1z));
    const bool miss = (farv < nearv);
    if (miss) { nearv = 1e9f; farv = 1e9f; }
    nearv = fmaxf(nearv, 0.05f);
    const float sample_dist = (farv - nearv) * (1.0f / 64.0f);

    // ---- per-lane unit weights (lane j owns hidden unit j) ----
    const float wS = w_sigma[lane];
    const float wR = W_rgb[3 * lane + 0];
    const float wG = W_rgb[3 * lane + 1];
    const float wB = W_rgb[3 * lane + 2];

    // ---- per-ray affine layer-1: a_j(z) = c_j + m_j*z ----
    float cj, mj;
    {
        float w1x = W1[lane], w1y = W1[64 + lane], w1z = W1[128 + lane];
        float eox = ox, eoy = oy, eoz = oz, msc = 1.0f;
        if (miss) {
            eox = clamp1(fmaf(dx, 1e9f, ox));
            eoy = clamp1(fmaf(dy, 1e9f, oy));
            eoz = clamp1(fmaf(dz, 1e9f, oz));
            msc = 0.0f;
        }
        cj = fmaf(eox, w1x, fmaf(eoy, w1y, fmaf(eoz, w1z, b1[lane])));
        mj = msc * fmaf(dx, w1x, fmaf(dy, w1y, dz * w1z));
    }

    // ---- piecewise-linear MLP setup (sign form) --------------------------
    // relu(c+mz): m>0 unit turns ON at knee (payload +w(m,c)); m<0 unit is ON
    // below its knee (base w(c+mz), payload -w(m,c) turns it off); m==0 unit
    // contributes w*relu(c) always.  pre_X(z) = (Pp+prefB_k) + (Qp+prefA_k)z.
    const bool m0 = (mj == 0.0f);           // includes all lanes of miss rays
    const bool mneg = (mj < 0.0f);
    float knee = m0 ? 3e38f : (-cj * fast_rcp(mj));
    float t  = m0 ? 0.0f : (mneg ? -1.0f : 1.0f);
    float tm = t * mj, tc = t * cj;
    float pc = mneg ? cj : (m0 ? fmaxf(cj, 0.0f) : 0.0f);  // always-on base /wX
    float qc = mneg ? mj : 0.0f;

    // ---- unique 32-bit sort key: ordered-uint(knee), low 6 bits = lane ---
    // Total order with stable tie-break -> scatter is a bijection (no
    // zero-init needed).  Truncating 6 mantissa LSBs only reorders knees
    // within 2^-17 relative of each other: misclassification window ~1e-5
    // wide where the unit's contribution is ~0 -> error negligible.
    unsigned kb  = __float_as_uint(knee);
    unsigned ord = kb ^ ((kb & 0x80000000u) ? 0xFFFFFFFFu : 0x80000000u);
    unsigned key = (ord & ~63u) | (unsigned)lane;

    float* keyU = s_zmid[wv];    // key array (dead after the rank below)
    float* kneeS = s_kne[wv];
    keyU[lane] = __uint_as_float(key);

    // brute-force rank over unique keys: 1 cmp + 1 add per element
    int p = 0;
#pragma unroll
    for (int g = 0; g < 16; ++g) {
        v4f q = *(const v4f*)&keyU[4 * g];
        p += (int)(__float_as_uint(q.x) < key);
        p += (int)(__float_as_uint(q.y) < key);
        p += (int)(__float_as_uint(q.z) < key);
        p += (int)(__float_as_uint(q.w) < key);
    }
    kneeS[p] = knee;
    *(v4f*)&s_pref[wv][p][0] = (v4f){wS * tm, wS * tc, wR * tm, wR * tc};
    *(v4f*)&s_pref[wv][p][4] = (v4f){wG * tm, wG * tc, wB * tm, wB * tc};

    // base sums (order-independent) — these are the table's k=0 values
    const float bs0 = b_sigma[0];
    float QpS = wave_sum_dpp(wS * qc), PpS = wave_sum_dpp(wS * pc) + bs0;
    float QpR = wave_sum_dpp(wR * qc), PpR = wave_sum_dpp(wR * pc) + b_rgb[0];
    float QpG = wave_sum_dpp(wG * qc), PpG = wave_sum_dpp(wG * pc) + b_rgb[1];
    float QpB = wave_sum_dpp(wB * qc), PpB = wave_sum_dpp(wB * pc) + b_rgb[2];

    // read payloads in sorted order, scan, write table slot lane+1 (= prefix
    // over first lane+1 sorted elements, plus the base) ; lane0 writes slot 0
    v4f d0 = *(const v4f*)&s_pref[wv][lane][0];
    v4f d1 = *(const v4f*)&s_pref[wv][lane][4];
    float own_knee = kneeS[lane];

    float iAs = scan_add_dpp(d0.x) + QpS, iBs = scan_add_dpp(d0.y) + PpS;
    float iAr = scan_add_dpp(d0.z) + QpR, iBr = scan_add_dpp(d0.w) + PpR;
    float iAg = scan_add_dpp(d1.x) + QpG, iBg = scan_add_dpp(d1.y) + PpG;
    float iAb = scan_add_dpp(d1.z) + QpB, iBb = scan_add_dpp(d1.w) + PpB;

    *(v4f*)&s_pref[wv][lane + 1][0] = (v4f){iAs, iBs, iAr, iBr};
    *(v4f*)&s_pref[wv][lane + 1][4] = (v4f){iAg, iBg, iAb, iBb};
    if (lane == 0) {
        *(v4f*)&s_pref[wv][0][0] = (v4f){QpS, PpS, QpR, PpR};
        *(v4f*)&s_pref[wv][0][4] = (v4f){QpG, PpG, QpB, PpB};
    }

    // ---- coarse samples + sigma via one-fma table eval ----
    float z = nearv + (farv - nearv) * ((float)lane * (1.0f / 63.0f));
    float sigma;
    {
        int k = rank2<false>(kneeS, own_knee, z);
        v2f ab = *(const v2f*)&s_pref[wv][k][0];   // {A_s, B_s}
        sigma = softplus_f(fmaf(ab.x, z, ab.y));
    }

    // ---- coarse alpha compositing -> weights ----
    float z_next = fdpp<DPP_WF_SL1>(0.0f, z);
    float delta  = (lane < 63) ? (z_next - z) : sample_dist;
    float alpha  = 1.0f - __expf(-delta * sigma);
    float v      = 1.0f - alpha + 1e-15f;
    float incl   = scan_mul_dpp(v);
    float trans  = fdpp<DPP_WF_SR1>(1.0f, incl);   // lane0 -> 1.0
    float w = alpha * trans;

    // ---- sample_pdf: unnormalized scan, total from lane63 of same scan ----
    float wgt = (lane >= 1 && lane <= 62) ? (w + 1e-5f) : 0.0f;
    float cumw = scan_add_dpp(wgt);
    float total = lane63_bcast(cumw);
    float cdf_incl = cumw * fast_rcp(total);

    float zmid = 0.5f * (z + z_next);
    float cdfv = (lane < 63) ? cdf_incl : 2.0f;    // sentinel
    s_zmid[wv][lane] = (lane < 63) ? zmid : 0.0f;  // keyU dead -> reuse
    s_cdf [wv][lane] = cdfv;

    float u = 0.0078125f + (float)lane * 0.015625f;
    int ind = rank2<true>(s_cdf[wv], cdfv, u);
    int below = ind - 1;
    int above = (ind < 62) ? ind : 62;
    float cb = s_cdf[wv][below], ca = s_cdf[wv][above];
    float bb = s_zmid[wv][below], ba = s_zmid[wv][above];
    float denom = ca - cb;
    if (denom < 1e-5f) denom = 1.0f;
    float tt = (u - cb) * fast_rcp(denom);
    float nz = fmaf(tt, ba - bb, bb);

    // ---- rank-merge concat(z, new_z) -> 128 sorted ----
    s_zmid[wv][lane] = z;      // array of z's   (z_lane == own)
    s_cdf [wv][lane] = nz;     // array of nz's  (nz     == own)
    int pa  = lane + rank2<false>(s_cdf [wv], nz, z);
    int pb2 = lane + rank2<true >(s_zmid[wv], z,  nz);
    s_zall[wv][pa]  = z;
    s_zall[wv][pb2] = nz;

    v2f za = *(const v2f*)&s_zall[wv][2 * lane];
    float za0 = za.x;
    float za1 = za.y;

    // ---- fine MLP via one-fma table eval (both samples, 4 channels) ----
    int k0 = rank2<false>(kneeS, own_knee, za0);
    int k1 = rank2<false>(kneeS, own_knee, za1);
    v4f A0 = *(const v4f*)&s_pref[wv][k0][0];
    v4f A1 = *(const v4f*)&s_pref[wv][k0][4];
    v4f B0 = *(const v4f*)&s_pref[wv][k1][0];
    v4f B1 = *(const v4f*)&s_pref[wv][k1][4];

    float sg0 = softplus_f(fmaf(A0.x, za0, A0.y));
    float r0  = sigmoid_f (fmaf(A0.z, za0, A0.w));
    float g0  = sigmoid_f (fmaf(A1.x, za0, A1.y));
    float bl0 = sigmoid_f (fmaf(A1.z, za0, A1.w));
    float sg1 = softplus_f(fmaf(B0.x, za1, B0.y));
    float r1  = sigmoid_f (fmaf(B0.z, za1, B0.w));
    float g1  = sigmoid_f (fmaf(B1.x, za1, B1.y));
    float bl1 = sigmoid_f (fmaf(B1.z, za1, B1.w));

    // ---- fine compositing over 128 samples (2/lane) ----
    float zn0 = fdpp<DPP_WF_SL1>(0.0f, za0);
    float d0f = za1 - za0;
    float d1f = (lane < 63) ? (zn0 - za1) : sample_dist;
    float a0 = 1.0f - __expf(-d0f * sg0);
    float a1 = 1.0f - __expf(-d1f * sg1);
    float v0 = 1.0f - a0 + 1e-15f;
    float v1 = 1.0f - a1 + 1e-15f;
    float local = v0 * v1;
    float incl2 = scan_mul_dpp(local);
    float eprod = fdpp<DPP_WF_SR1>(1.0f, incl2);   // lane0 -> 1.0
    float w0 = a0 * eprod;
    float w1 = a1 * (eprod * v0);

    float wsum = wave_sum_dpp(w0 + w1);
    float rs   = wave_sum_dpp(fmaf(w0, r0,  w1 * r1));
    float gs   = wave_sum_dpp(fmaf(w0, g0,  w1 * g1));
    float bs   = wave_sum_dpp(fmaf(w0, bl0, w1 * bl1));

    if (lane == 0) {
        float bg = 1.0f - wsum;
        out[ray * 3 + 0] = rs + bg;
        out[ray * 3 + 1] = gs + bg;
        out[ray * 3 + 2] = bs + bg;
    }
}

extern "C" void kernel_launch(void* const* d_in, const int* in_sizes, int n_in,
                              void* d_out, int out_size, void* d_ws, size_t ws_size,
                              hipStream_t stream) {
    const float* rays_o  = (const float*)d_in[0];
    const float* rays_d  = (const float*)d_in[1];
    const float* W1      = (const float*)d_in[2];
    const float* b1      = (const float*)d_in[3];
    const float* w_sigma = (const float*)d_in[4];
    const float* b_sigma = (const float*)d_in[5];
    const float* W_rgb   = (const float*)d_in[6];
    const float* b_rgb   = (const float*)d_in[7];
    float* out = (float*)d_out;

    const int n_rays = in_sizes[0] / 3;
    dim3 grid((n_rays + WAVES_PER_BLOCK - 1) / WAVES_PER_BLOCK);
    dim3 block(WAVES_PER_BLOCK * 64);
    hipLaunchKernelGGL(nerf_render_kernel, grid, block, 0, stream,
                       rays_o, rays_d, W1, b1, w_sigma, b_sigma, W_rgb, b_rgb, out);
}